// Round 6
// baseline (221.989 us; speedup 1.0000x reference)
//
#include <hip/hip_runtime.h>
#include <hip/hip_bf16.h>

typedef __bf16 bf16_t;
typedef __attribute__((ext_vector_type(8))) __bf16 bf16x8;
typedef __attribute__((ext_vector_type(4))) __bf16 bf16x4;
typedef __attribute__((ext_vector_type(4))) float f32x4;

// Problem constants
// B=2, N=2048, D=256, H=8, M=2, NN=2048, K=8, dh=32

// ---------------------------------------------------------------------------
// Kernel 0: convert weights to bf16
// ---------------------------------------------------------------------------
__global__ __launch_bounds__(256) void wconv_kernel(const float* __restrict__ w_in,
                                                    const float* __restrict__ w_out,
                                                    bf16_t* __restrict__ w_in_b,
                                                    bf16_t* __restrict__ w_out_b) {
    int i = blockIdx.x * 256 + threadIdx.x;
    if (i < 768 * 256) w_in_b[i] = (bf16_t)w_in[i];
    if (i < 256 * 256) w_out_b[i] = (bf16_t)w_out[i];
}

// ---------------------------------------------------------------------------
// Kernel 1: KNN top-8, one WAVE per query. 16 queries per 1024-thread block;
// block stages all 2048 points (x,y,z,|p|^2) in LDS once. Each lane keeps a
// sorted top-8 of its 32 candidates (j = t*64 + lane, stride-1 LDS reads,
// within-lane idx ascending), then 8 rounds of wave-wide lexicographic
// (d2, idx) min via shfl_xor + pop-shift. Matches lax.top_k stable ordering.
// Distance formula replicates reference fp32 evaluation order, no fma.
// ---------------------------------------------------------------------------
__global__ __launch_bounds__(1024) void knn_kernel(const float* __restrict__ cur_pts,
                                                   const float* __restrict__ nbr_pts,
                                                   int* __restrict__ idx_out) {
    int p = blockIdx.y;  // 0..5 : 0,1 = current batches; 2..5 = (m*2+b)
    const float* pts = (p < 2) ? (cur_pts + (size_t)p * 2048 * 3)
                               : (nbr_pts + (size_t)(p - 2) * 2048 * 3);

    __shared__ __align__(16) float4 spts[2048];

    int tid = threadIdx.x;
    for (int i = tid; i < 2048; i += 1024) {
        float x = pts[i * 3 + 0], y = pts[i * 3 + 1], z = pts[i * 3 + 2];
        float sq = __fadd_rn(__fadd_rn(__fmul_rn(x, x), __fmul_rn(y, y)), __fmul_rn(z, z));
        spts[i] = make_float4(x, y, z, sq);
    }
    __syncthreads();

    int wave = tid >> 6, lane = tid & 63;
    int q = blockIdx.x * 16 + wave;
    float4 qp4 = spts[q];

    float dist[8];
    int di[8];
#pragma unroll
    for (int r = 0; r < 8; r++) { dist[r] = 3.4e38f; di[r] = 0x7fffffff; }

    for (int t = 0; t < 32; t++) {
        int j = t * 64 + lane;
        float4 pp = spts[j];
        float dot = __fadd_rn(__fadd_rn(__fmul_rn(qp4.x, pp.x), __fmul_rn(qp4.y, pp.y)),
                              __fmul_rn(qp4.z, pp.z));
        float d2 = __fsub_rn(__fadd_rn(qp4.w, pp.w), __fmul_rn(2.0f, dot));
        if (d2 < dist[7]) {
#pragma unroll
            for (int r = 7; r >= 1; --r) {
                bool cm = d2 < dist[r - 1];
                bool cr = d2 < dist[r];
                float nd = cm ? dist[r - 1] : (cr ? d2 : dist[r]);
                int ni = cm ? di[r - 1] : (cr ? j : di[r]);
                dist[r] = nd; di[r] = ni;
            }
            if (d2 < dist[0]) { dist[0] = d2; di[0] = j; }
        }
    }

    // 8 rounds: wave-wide lexicographic (d2, idx) min, winner lane pops.
    int res[8];
#pragma unroll
    for (int r = 0; r < 8; r++) {
        float bd = dist[0];
        int bi = di[0];
#pragma unroll
        for (int m = 1; m < 64; m <<= 1) {
            float od = __shfl_xor(bd, m);
            int oi = __shfl_xor(bi, m);
            if (od < bd || (od == bd && oi < bi)) { bd = od; bi = oi; }
        }
        res[r] = bi;
        bool win = (di[0] == bi);
#pragma unroll
        for (int k = 0; k < 7; k++) {
            dist[k] = win ? dist[k + 1] : dist[k];
            di[k]   = win ? di[k + 1]   : di[k];
        }
        if (win) { dist[7] = 3.4e38f; di[7] = 0x7fffffff; }
    }

    if (lane == 0) {
        int4* o = (int4*)(idx_out + ((size_t)p * 2048 + q) * 8);
        o[0] = make_int4(res[0], res[1], res[2], res[3]);
        o[1] = make_int4(res[4], res[5], res[6], res[7]);
    }
}

// ---------------------------------------------------------------------------
// Kernel 2: gather neighbor features, edge = f - mean(nbr). One block per
// query (64 threads x float4). Writes bf16 edge features in the layouts the
// GEMMs consume (cur_edge [B*N,256]; all_nbr [B, M*NN, 256]).
// ---------------------------------------------------------------------------
__global__ __launch_bounds__(64) void edge_kernel(const float* __restrict__ cur_feat,
                                                  const float* __restrict__ nbr_feat,
                                                  const int* __restrict__ idx_buf,
                                                  bf16_t* __restrict__ cur_edge,
                                                  bf16_t* __restrict__ all_nbr) {
    int blk = blockIdx.x;
    int p = blk >> 11, q = blk & 2047;
    const float* feat;
    bf16_t* outp;
    if (p < 2) {
        feat = cur_feat + (size_t)p * 2048 * 256;
        outp = cur_edge + ((size_t)p * 2048 + q) * 256;
    } else {
        int mb = p - 2;
        int m = mb >> 1, bb = mb & 1;
        feat = nbr_feat + (size_t)mb * 2048 * 256;
        outp = all_nbr + ((size_t)bb * 4096 + m * 2048 + q) * 256;
    }
    const int* idx = idx_buf + ((size_t)p * 2048 + q) * 8;
    int t = threadIdx.x;
    float4 self = ((const float4*)(feat + (size_t)q * 256))[t];
    float sx = 0.f, sy = 0.f, sz = 0.f, sw = 0.f;
#pragma unroll
    for (int r = 0; r < 8; r++) {
        float4 f = ((const float4*)(feat + (size_t)idx[r] * 256))[t];
        sx += f.x; sy += f.y; sz += f.z; sw += f.w;
    }
    bf16x4 v;
    v[0] = (bf16_t)(self.x - sx * 0.125f);
    v[1] = (bf16_t)(self.y - sy * 0.125f);
    v[2] = (bf16_t)(self.z - sz * 0.125f);
    v[3] = (bf16_t)(self.w - sw * 0.125f);
    *(bf16x4*)(outp + 4 * t) = v;
}

// ---------------------------------------------------------------------------
// Kernel 3: QKV projections via bf16 MFMA. z=0: qp (scaled by 1/sqrt(32)),
// z=1: kp, z=2: vp stored transposed per head [b,h,dh,kv].
// Block 256 = 4 waves of 32x32 -> 64x64 tile, K=256.
// ---------------------------------------------------------------------------
__global__ __launch_bounds__(256) void qkv_kernel(const bf16_t* __restrict__ cur_edge,
                                                  const bf16_t* __restrict__ all_nbr,
                                                  const bf16_t* __restrict__ w_in,
                                                  const float* __restrict__ b_in,
                                                  bf16_t* __restrict__ qp,
                                                  bf16_t* __restrict__ kp,
                                                  bf16_t* __restrict__ vpT) {
    int z = blockIdx.z;
    int Mrows = (z == 0) ? 4096 : 8192;
    int m0base = blockIdx.y * 64;
    if (m0base >= Mrows) return;
    const bf16_t* A = (z == 0) ? cur_edge : all_nbr;
    const bf16_t* W = w_in + (size_t)z * 256 * 256;

    int wave = threadIdx.x >> 6, lane = threadIdx.x & 63;
    int wr = wave >> 1, wc = wave & 1;
    int m0 = m0base + wr * 32;
    int n0 = blockIdx.x * 64 + wc * 32;
    int lr = lane & 15, lg = lane >> 4;

    f32x4 acc[2][2] = {};
    for (int kc = 0; kc < 256; kc += 32) {
        bf16x8 a[2], b[2];
#pragma unroll
        for (int i = 0; i < 2; i++)
            a[i] = *(const bf16x8*)(A + (size_t)(m0 + i * 16 + lr) * 256 + kc + lg * 8);
#pragma unroll
        for (int i = 0; i < 2; i++)
            b[i] = *(const bf16x8*)(W + (size_t)(n0 + i * 16 + lr) * 256 + kc + lg * 8);
#pragma unroll
        for (int i = 0; i < 2; i++)
#pragma unroll
            for (int j = 0; j < 2; j++)
                acc[i][j] = __builtin_amdgcn_mfma_f32_16x16x32_bf16(a[i], b[j], acc[i][j], 0, 0, 0);
    }

    const float inv_s = 0.17677669529663687f;  // 1/sqrt(32)
#pragma unroll
    for (int i = 0; i < 2; i++)
#pragma unroll
        for (int j = 0; j < 2; j++)
#pragma unroll
            for (int r = 0; r < 4; r++) {
                int mm = m0 + i * 16 + lg * 4 + r;
                int nn = n0 + j * 16 + lr;
                float v = acc[i][j][r] + b_in[z * 256 + nn];
                if (z == 0) {
                    qp[(size_t)mm * 256 + nn] = (bf16_t)(v * inv_s);
                } else if (z == 1) {
                    kp[(size_t)mm * 256 + nn] = (bf16_t)v;
                } else {
                    int bb = mm >> 12, kv = mm & 4095, h = nn >> 5, dd = nn & 31;
                    vpT[(((size_t)bb * 8 + h) * 32 + dd) * 4096 + kv] = (bf16_t)v;
                }
            }
}

// ---------------------------------------------------------------------------
// Kernel 4: cross attention, kv-SPLIT partial softmax + 1-deep register
// prefetch. Scores tiny (|s|<<1) so no max-subtraction; partial chunks
// combine by pure addition downstream. Per-wave structure = round-4 proven
// layout (32 q rows/wave, kv tile 32, each kfrag feeds 2 QK MFMAs); the
// unroll-2 loop prefetches tile i+1's K/V frags into a static register
// double-buffer while computing tile i. sched_barrier(0) after each
// prefetch-issue pins the loads above the compute phase (issue-early).
// __launch_bounds__(256,4): VGPR cap 128 so both buffers stay resident.
// ---------------------------------------------------------------------------
__global__ __launch_bounds__(256, 4) void attn_kernel(const bf16_t* __restrict__ qp,
                                                      const bf16_t* __restrict__ kp,
                                                      const bf16_t* __restrict__ vpT,
                                                      bf16_t* __restrict__ Opart,
                                                      float* __restrict__ Lpart) {
    int bh = blockIdx.y;
    int b = bh >> 3, h = bh & 7;
    int c = blockIdx.z;  // kv chunk 0..3
    int wave = threadIdx.x >> 6, lane = threadIdx.x & 63;
    int lr = lane & 15, lg = lane >> 4;
    int q0 = blockIdx.x * 128 + wave * 32;

    const bf16_t* Qb = qp + ((size_t)b * 2048 + q0) * 256 + h * 32;
    const bf16_t* Kb = kp + (size_t)b * 4096 * 256 + h * 32;
    const bf16_t* Vb = vpT + ((size_t)b * 8 + h) * 32 * 4096;

    __shared__ __align__(16) bf16_t P_lds[4][2][16][32];

    bf16x8 qfrag[2];
    qfrag[0] = *(const bf16x8*)(Qb + (size_t)lr * 256 + lg * 8);
    qfrag[1] = *(const bf16x8*)(Qb + (size_t)(16 + lr) * 256 + lg * 8);

    f32x4 oacc[2][2] = {};
    float lsum[2][4] = {};
    const f32x4 zf = {0.f, 0.f, 0.f, 0.f};

    const bf16_t* Kp0 = Kb + (size_t)lr * 256 + lg * 8;   // + kv*256
    const bf16_t* Vp0 = Vb + (size_t)lr * 4096 + lg * 8;  // + kv ; +16*4096 for ds=1

    bf16x8 kfA[2], vfA[2], kfB[2], vfB[2];

#define LOADKV(KF, VF, KV0)                                                    \
    {                                                                          \
        KF[0] = *(const bf16x8*)(Kp0 + (size_t)(KV0) * 256);                   \
        KF[1] = *(const bf16x8*)(Kp0 + (size_t)((KV0) + 16) * 256);            \
        VF[0] = *(const bf16x8*)(Vp0 + (KV0));                                 \
        VF[1] = *(const bf16x8*)(Vp0 + 16 * 4096 + (KV0));                     \
    }

#define COMPUTE(KF, VF)                                                        \
    {                                                                          \
        _Pragma("unroll")                                                      \
        for (int ms = 0; ms < 2; ms++) {                                       \
            f32x4 s0 = __builtin_amdgcn_mfma_f32_16x16x32_bf16(qfrag[ms], KF[0], zf, 0, 0, 0); \
            f32x4 s1 = __builtin_amdgcn_mfma_f32_16x16x32_bf16(qfrag[ms], KF[1], zf, 0, 0, 0); \
            _Pragma("unroll")                                                  \
            for (int r = 0; r < 4; r++) {                                      \
                float p0 = __expf(s0[r]);                                      \
                float p1 = __expf(s1[r]);                                      \
                lsum[ms][r] += p0 + p1;                                        \
                P_lds[wave][ms][lg * 4 + r][lr] = (bf16_t)p0;                  \
                P_lds[wave][ms][lg * 4 + r][16 + lr] = (bf16_t)p1;             \
            }                                                                  \
        }                                                                      \
        _Pragma("unroll")                                                      \
        for (int ms = 0; ms < 2; ms++) {                                       \
            bf16x8 pf = *(const bf16x8*)(&P_lds[wave][ms][lr][lg * 8]);        \
            oacc[ms][0] = __builtin_amdgcn_mfma_f32_16x16x32_bf16(pf, VF[0], oacc[ms][0], 0, 0, 0); \
            oacc[ms][1] = __builtin_amdgcn_mfma_f32_16x16x32_bf16(pf, VF[1], oacc[ms][1], 0, 0, 0); \
        }                                                                      \
    }

    int kv_lo = c * 1024, kv_hi = kv_lo + 1024;
    LOADKV(kfA, vfA, kv_lo)
    for (int kv0 = kv_lo; kv0 < kv_hi; kv0 += 64) {
        LOADKV(kfB, vfB, kv0 + 32)
        __builtin_amdgcn_sched_barrier(0);
        COMPUTE(kfA, vfA)
        if (kv0 + 64 < kv_hi) { LOADKV(kfA, vfA, kv0 + 64) }
        __builtin_amdgcn_sched_barrier(0);
        COMPUTE(kfB, vfB)
    }
#undef LOADKV
#undef COMPUTE

    // reduce row sums across the 16 lanes sharing the same row group
#pragma unroll
    for (int ms = 0; ms < 2; ms++)
#pragma unroll
        for (int r = 0; r < 4; r++) {
            float s = lsum[ms][r];
            s += __shfl_xor(s, 1);
            s += __shfl_xor(s, 2);
            s += __shfl_xor(s, 4);
            s += __shfl_xor(s, 8);
            lsum[ms][r] = s;
        }

    // partial writes: unnormalized O (bf16) and row-sum l (f32, lane lr==0)
#pragma unroll
    for (int ms = 0; ms < 2; ms++)
#pragma unroll
        for (int r = 0; r < 4; r++) {
            int qq = q0 + ms * 16 + lg * 4 + r;
            if (lr == 0)
                Lpart[(((size_t)c * 2 + b) * 8 + h) * 2048 + qq] = lsum[ms][r];
#pragma unroll
            for (int ds = 0; ds < 2; ds++) {
                int dd = h * 32 + ds * 16 + lr;
                Opart[(((size_t)c * 2 + b) * 2048 + qq) * 256 + dd] = (bf16_t)oacc[ms][ds][r];
            }
        }
}

// ---------------------------------------------------------------------------
// Kernel 4b: combine kv-split partials: o = (sum_c O_c) / (sum_c l_c).
// 131072 threads, each handles 8 contiguous cols of one row.
// ---------------------------------------------------------------------------
__global__ __launch_bounds__(256) void attn_combine(const bf16_t* __restrict__ Opart,
                                                    const float* __restrict__ Lpart,
                                                    bf16_t* __restrict__ o_buf) {
    int t = blockIdx.x * 256 + threadIdx.x;  // 0..131071
    int row = t >> 5;            // 0..4095  (b*2048+q)
    int c8 = (t & 31) * 8;       // col start, all 8 cols share one head
    int b = row >> 11, q = row & 2047, h = c8 >> 5;

    float acc[8] = {};
    float l = 0.f;
#pragma unroll
    for (int c = 0; c < 4; c++) {
        bf16x8 v = *(const bf16x8*)(Opart + (((size_t)c * 2 + b) * 2048 + q) * 256 + c8);
#pragma unroll
        for (int j = 0; j < 8; j++) acc[j] += (float)v[j];
        l += Lpart[(((size_t)c * 2 + b) * 8 + h) * 2048 + q];
    }
    float rl = 1.0f / l;
    bf16x8 o;
#pragma unroll
    for (int j = 0; j < 8; j++) o[j] = (bf16_t)(acc[j] * rl);
    *(bf16x8*)(o_buf + (size_t)row * 256 + c8) = o;
}

// ---------------------------------------------------------------------------
// Kernel 5: out = o @ out_w^T + out_b + points @ spatial_w^T + spatial_b
// ---------------------------------------------------------------------------
__global__ __launch_bounds__(256) void outproj_kernel(const bf16_t* __restrict__ o_buf,
                                                      const bf16_t* __restrict__ w_out,
                                                      const float* __restrict__ b_out,
                                                      const float* __restrict__ cur_pts,
                                                      const float* __restrict__ sw,
                                                      const float* __restrict__ sb,
                                                      float* __restrict__ out) {
    int wave = threadIdx.x >> 6, lane = threadIdx.x & 63;
    int wr = wave >> 1, wc = wave & 1;
    int m0 = blockIdx.y * 64 + wr * 32;
    int n0 = blockIdx.x * 64 + wc * 32;
    int lr = lane & 15, lg = lane >> 4;

    f32x4 acc[2][2] = {};
    for (int kc = 0; kc < 256; kc += 32) {
        bf16x8 a[2], b[2];
#pragma unroll
        for (int i = 0; i < 2; i++)
            a[i] = *(const bf16x8*)(o_buf + (size_t)(m0 + i * 16 + lr) * 256 + kc + lg * 8);
#pragma unroll
        for (int i = 0; i < 2; i++)
            b[i] = *(const bf16x8*)(w_out + (size_t)(n0 + i * 16 + lr) * 256 + kc + lg * 8);
#pragma unroll
        for (int i = 0; i < 2; i++)
#pragma unroll
            for (int j = 0; j < 2; j++)
                acc[i][j] = __builtin_amdgcn_mfma_f32_16x16x32_bf16(a[i], b[j], acc[i][j], 0, 0, 0);
    }

#pragma unroll
    for (int i = 0; i < 2; i++)
#pragma unroll
        for (int j = 0; j < 2; j++)
#pragma unroll
            for (int r = 0; r < 4; r++) {
                int mm = m0 + i * 16 + lg * 4 + r;
                int nn = n0 + j * 16 + lr;
                const float* pp = cur_pts + (size_t)mm * 3;
                float sp = pp[0] * sw[nn * 3 + 0] + pp[1] * sw[nn * 3 + 1] + pp[2] * sw[nn * 3 + 2] + sb[nn];
                out[(size_t)mm * 256 + nn] = acc[i][j][r] + b_out[nn] + sp;
            }
}

// ---------------------------------------------------------------------------
extern "C" void kernel_launch(void* const* d_in, const int* in_sizes, int n_in,
                              void* d_out, int out_size, void* d_ws, size_t ws_size,
                              hipStream_t stream) {
    const float* cur_pts  = (const float*)d_in[0];
    const float* cur_feat = (const float*)d_in[1];
    const float* nbr_pts  = (const float*)d_in[2];
    const float* nbr_feat = (const float*)d_in[3];
    const float* in_w     = (const float*)d_in[4];
    const float* in_b     = (const float*)d_in[5];
    const float* out_w    = (const float*)d_in[6];
    const float* out_b    = (const float*)d_in[7];
    const float* sw       = (const float*)d_in[8];
    const float* sb       = (const float*)d_in[9];

    char* ws = (char*)d_ws;
    bf16_t* w_in_b  = (bf16_t*)(ws + 0);          //  768*256*2 = 393216
    bf16_t* w_out_b = (bf16_t*)(ws + 393216);     //  256*256*2 = 131072
    int*    idx_buf = (int*)(ws + 524288);        //  6*2048*8*4 = 393216
    bf16_t* cur_edge = (bf16_t*)(ws + 917504);    //  4096*256*2 = 2097152
    bf16_t* all_nbr  = (bf16_t*)(ws + 3014656);   //  8192*256*2 = 4194304
    bf16_t* qp  = (bf16_t*)(ws + 7208960);        //  4096*256*2
    bf16_t* kp  = (bf16_t*)(ws + 9306112);        //  8192*256*2
    bf16_t* vpT = (bf16_t*)(ws + 13500416);       //  2*8*32*4096*2
    bf16_t* o_buf = (bf16_t*)(ws + 17694720);     //  4096*256*2 = 2097152
    bf16_t* Opart = (bf16_t*)(ws + 19791872);     //  4*2*2048*256*2 = 8388608
    float*  Lpart = (float*)(ws + 28180480);      //  4*2*8*2048*4 = 524288  (end 28704768)
    float* outp = (float*)d_out;

    wconv_kernel<<<dim3(768), dim3(256), 0, stream>>>(in_w, out_w, w_in_b, w_out_b);
    knn_kernel<<<dim3(128, 6), dim3(1024), 0, stream>>>(cur_pts, nbr_pts, idx_buf);
    edge_kernel<<<dim3(12288), dim3(64), 0, stream>>>(cur_feat, nbr_feat, idx_buf, cur_edge, all_nbr);
    qkv_kernel<<<dim3(4, 128, 3), dim3(256), 0, stream>>>(cur_edge, all_nbr, w_in_b, in_b, qp, kp, vpT);
    attn_kernel<<<dim3(16, 16, 4), dim3(256), 0, stream>>>(qp, kp, vpT, Opart, Lpart);
    attn_combine<<<dim3(512), dim3(256), 0, stream>>>(Opart, Lpart, o_buf);
    outproj_kernel<<<dim3(4, 64), dim3(256), 0, stream>>>(o_buf, w_out_b, out_b, cur_pts, sw, sb, outp);
}

// Round 7
// 202.630 us; speedup vs baseline: 1.0955x; 1.0955x over previous
//
#include <hip/hip_runtime.h>
#include <hip/hip_bf16.h>

typedef __bf16 bf16_t;
typedef __attribute__((ext_vector_type(8))) __bf16 bf16x8;
typedef __attribute__((ext_vector_type(4))) __bf16 bf16x4;
typedef __attribute__((ext_vector_type(4))) float f32x4;

// Problem constants
// B=2, N=2048, D=256, H=8, M=2, NN=2048, K=8, dh=32

// ---------------------------------------------------------------------------
// Kernel 0: convert weights to bf16
// ---------------------------------------------------------------------------
__global__ __launch_bounds__(256) void wconv_kernel(const float* __restrict__ w_in,
                                                    const float* __restrict__ w_out,
                                                    bf16_t* __restrict__ w_in_b,
                                                    bf16_t* __restrict__ w_out_b) {
    int i = blockIdx.x * 256 + threadIdx.x;
    if (i < 768 * 256) w_in_b[i] = (bf16_t)w_in[i];
    if (i < 256 * 256) w_out_b[i] = (bf16_t)w_out[i];
}

// ---------------------------------------------------------------------------
// Kernel 1: KNN top-8, one WAVE per query. 16 queries per 1024-thread block;
// block stages all 2048 points (x,y,z,|p|^2) in LDS once. Each lane keeps a
// sorted top-8 of its 32 candidates (j = t*64 + lane, stride-1 LDS reads,
// within-lane idx ascending), then 8 rounds of wave-wide lexicographic
// (d2, idx) min via shfl_xor + pop-shift. Matches lax.top_k stable ordering.
// Distance formula replicates reference fp32 evaluation order, no fma.
// ---------------------------------------------------------------------------
__global__ __launch_bounds__(1024) void knn_kernel(const float* __restrict__ cur_pts,
                                                   const float* __restrict__ nbr_pts,
                                                   int* __restrict__ idx_out) {
    int p = blockIdx.y;  // 0..5 : 0,1 = current batches; 2..5 = (m*2+b)
    const float* pts = (p < 2) ? (cur_pts + (size_t)p * 2048 * 3)
                               : (nbr_pts + (size_t)(p - 2) * 2048 * 3);

    __shared__ __align__(16) float4 spts[2048];

    int tid = threadIdx.x;
    for (int i = tid; i < 2048; i += 1024) {
        float x = pts[i * 3 + 0], y = pts[i * 3 + 1], z = pts[i * 3 + 2];
        float sq = __fadd_rn(__fadd_rn(__fmul_rn(x, x), __fmul_rn(y, y)), __fmul_rn(z, z));
        spts[i] = make_float4(x, y, z, sq);
    }
    __syncthreads();

    int wave = tid >> 6, lane = tid & 63;
    int q = blockIdx.x * 16 + wave;
    float4 qp4 = spts[q];

    float dist[8];
    int di[8];
#pragma unroll
    for (int r = 0; r < 8; r++) { dist[r] = 3.4e38f; di[r] = 0x7fffffff; }

    for (int t = 0; t < 32; t++) {
        int j = t * 64 + lane;
        float4 pp = spts[j];
        float dot = __fadd_rn(__fadd_rn(__fmul_rn(qp4.x, pp.x), __fmul_rn(qp4.y, pp.y)),
                              __fmul_rn(qp4.z, pp.z));
        float d2 = __fsub_rn(__fadd_rn(qp4.w, pp.w), __fmul_rn(2.0f, dot));
        if (d2 < dist[7]) {
#pragma unroll
            for (int r = 7; r >= 1; --r) {
                bool cm = d2 < dist[r - 1];
                bool cr = d2 < dist[r];
                float nd = cm ? dist[r - 1] : (cr ? d2 : dist[r]);
                int ni = cm ? di[r - 1] : (cr ? j : di[r]);
                dist[r] = nd; di[r] = ni;
            }
            if (d2 < dist[0]) { dist[0] = d2; di[0] = j; }
        }
    }

    // 8 rounds: wave-wide lexicographic (d2, idx) min, winner lane pops.
    int res[8];
#pragma unroll
    for (int r = 0; r < 8; r++) {
        float bd = dist[0];
        int bi = di[0];
#pragma unroll
        for (int m = 1; m < 64; m <<= 1) {
            float od = __shfl_xor(bd, m);
            int oi = __shfl_xor(bi, m);
            if (od < bd || (od == bd && oi < bi)) { bd = od; bi = oi; }
        }
        res[r] = bi;
        bool win = (di[0] == bi);
#pragma unroll
        for (int k = 0; k < 7; k++) {
            dist[k] = win ? dist[k + 1] : dist[k];
            di[k]   = win ? di[k + 1]   : di[k];
        }
        if (win) { dist[7] = 3.4e38f; di[7] = 0x7fffffff; }
    }

    if (lane == 0) {
        int4* o = (int4*)(idx_out + ((size_t)p * 2048 + q) * 8);
        o[0] = make_int4(res[0], res[1], res[2], res[3]);
        o[1] = make_int4(res[4], res[5], res[6], res[7]);
    }
}

// ---------------------------------------------------------------------------
// Kernel 2: gather neighbor features, edge = f - mean(nbr). One block per
// query (64 threads x float4). Writes bf16 edge features in the layouts the
// GEMMs consume (cur_edge [B*N,256]; all_nbr [B, M*NN, 256]).
// ---------------------------------------------------------------------------
__global__ __launch_bounds__(64) void edge_kernel(const float* __restrict__ cur_feat,
                                                  const float* __restrict__ nbr_feat,
                                                  const int* __restrict__ idx_buf,
                                                  bf16_t* __restrict__ cur_edge,
                                                  bf16_t* __restrict__ all_nbr) {
    int blk = blockIdx.x;
    int p = blk >> 11, q = blk & 2047;
    const float* feat;
    bf16_t* outp;
    if (p < 2) {
        feat = cur_feat + (size_t)p * 2048 * 256;
        outp = cur_edge + ((size_t)p * 2048 + q) * 256;
    } else {
        int mb = p - 2;
        int m = mb >> 1, bb = mb & 1;
        feat = nbr_feat + (size_t)mb * 2048 * 256;
        outp = all_nbr + ((size_t)bb * 4096 + m * 2048 + q) * 256;
    }
    const int* idx = idx_buf + ((size_t)p * 2048 + q) * 8;
    int t = threadIdx.x;
    float4 self = ((const float4*)(feat + (size_t)q * 256))[t];
    float sx = 0.f, sy = 0.f, sz = 0.f, sw = 0.f;
#pragma unroll
    for (int r = 0; r < 8; r++) {
        float4 f = ((const float4*)(feat + (size_t)idx[r] * 256))[t];
        sx += f.x; sy += f.y; sz += f.z; sw += f.w;
    }
    bf16x4 v;
    v[0] = (bf16_t)(self.x - sx * 0.125f);
    v[1] = (bf16_t)(self.y - sy * 0.125f);
    v[2] = (bf16_t)(self.z - sz * 0.125f);
    v[3] = (bf16_t)(self.w - sw * 0.125f);
    *(bf16x4*)(outp + 4 * t) = v;
}

// ---------------------------------------------------------------------------
// Kernel 3: QKV projections via bf16 MFMA. z=0: qp (scaled by 1/sqrt(32)),
// z=1: kp, z=2: vp stored transposed per head [b,h,dh,kv].
// Block 256 = 4 waves of 32x32 -> 64x64 tile, K=256.
// ---------------------------------------------------------------------------
__global__ __launch_bounds__(256) void qkv_kernel(const bf16_t* __restrict__ cur_edge,
                                                  const bf16_t* __restrict__ all_nbr,
                                                  const bf16_t* __restrict__ w_in,
                                                  const float* __restrict__ b_in,
                                                  bf16_t* __restrict__ qp,
                                                  bf16_t* __restrict__ kp,
                                                  bf16_t* __restrict__ vpT) {
    int z = blockIdx.z;
    int Mrows = (z == 0) ? 4096 : 8192;
    int m0base = blockIdx.y * 64;
    if (m0base >= Mrows) return;
    const bf16_t* A = (z == 0) ? cur_edge : all_nbr;
    const bf16_t* W = w_in + (size_t)z * 256 * 256;

    int wave = threadIdx.x >> 6, lane = threadIdx.x & 63;
    int wr = wave >> 1, wc = wave & 1;
    int m0 = m0base + wr * 32;
    int n0 = blockIdx.x * 64 + wc * 32;
    int lr = lane & 15, lg = lane >> 4;

    f32x4 acc[2][2] = {};
    for (int kc = 0; kc < 256; kc += 32) {
        bf16x8 a[2], b[2];
#pragma unroll
        for (int i = 0; i < 2; i++)
            a[i] = *(const bf16x8*)(A + (size_t)(m0 + i * 16 + lr) * 256 + kc + lg * 8);
#pragma unroll
        for (int i = 0; i < 2; i++)
            b[i] = *(const bf16x8*)(W + (size_t)(n0 + i * 16 + lr) * 256 + kc + lg * 8);
#pragma unroll
        for (int i = 0; i < 2; i++)
#pragma unroll
            for (int j = 0; j < 2; j++)
                acc[i][j] = __builtin_amdgcn_mfma_f32_16x16x32_bf16(a[i], b[j], acc[i][j], 0, 0, 0);
    }

    const float inv_s = 0.17677669529663687f;  // 1/sqrt(32)
#pragma unroll
    for (int i = 0; i < 2; i++)
#pragma unroll
        for (int j = 0; j < 2; j++)
#pragma unroll
            for (int r = 0; r < 4; r++) {
                int mm = m0 + i * 16 + lg * 4 + r;
                int nn = n0 + j * 16 + lr;
                float v = acc[i][j][r] + b_in[z * 256 + nn];
                if (z == 0) {
                    qp[(size_t)mm * 256 + nn] = (bf16_t)(v * inv_s);
                } else if (z == 1) {
                    kp[(size_t)mm * 256 + nn] = (bf16_t)v;
                } else {
                    int bb = mm >> 12, kv = mm & 4095, h = nn >> 5, dd = nn & 31;
                    vpT[(((size_t)bb * 8 + h) * 32 + dd) * 4096 + kv] = (bf16_t)v;
                }
            }
}

// ---------------------------------------------------------------------------
// Kernel 4: cross attention, kv-SPLIT partial softmax + block-cooperative
// LDS staging. No max-subtraction (|s|<<1, ratio identical); partials
// combine by addition downstream.
//   - wave owns 16 q rows; block = 4 waves = 64 q rows; grid (32,16,4) =
//     2048 blocks = 8 blocks/CU -> 8 waves/SIMD TLP.
//   - per 32-kv tile: 256 threads cooperatively stage K-slice (32x32) +
//     V-slice (32x32) into a 4KB FRAGMENT-MAJOR LDS tile (addr = tid*16),
//     so staging writes AND all frag reads are linear: 0 bank conflicts,
//     4x less global issue/traffic than per-wave loads.
//   - T14 split: next tile's global load issues before the barrier, its
//     ds_write lands next iteration -> HBM/L2 latency hides under compute.
//   - P round-trips per-wave LDS in fragment-major order (read = lane*16,
//     linear; writes <=2-way) killing the old 8-way P-read conflict.
// ---------------------------------------------------------------------------
__global__ __launch_bounds__(256, 8) void attn_kernel(const bf16_t* __restrict__ qp,
                                                      const bf16_t* __restrict__ kp,
                                                      const bf16_t* __restrict__ vpT,
                                                      bf16_t* __restrict__ Opart,
                                                      float* __restrict__ Lpart) {
    int bh = blockIdx.y;
    int b = bh >> 3, h = bh & 7;
    int c = blockIdx.z;  // kv chunk 0..3
    int wave = threadIdx.x >> 6, lane = threadIdx.x & 63;
    int lr = lane & 15, lg = lane >> 4;
    int q0 = blockIdx.x * 64 + wave * 16;

    const bf16_t* Qb = qp + ((size_t)b * 2048 + q0) * 256 + h * 32;
    const bf16_t* Kb = kp + (size_t)b * 4096 * 256 + h * 32;
    const bf16_t* Vb = vpT + ((size_t)b * 8 + h) * 32 * 4096;

    // fragment-major staged K/V tile: elems [0,512)=kf0, [512,1024)=kf1,
    // [1024,1536)=vf0, [1536,2048)=vf1 ; each chunk = 64 lanes x 8 bf16
    __shared__ __align__(16) bf16_t KV[2048];
    // per-wave fragment-major P (16 q x 32 kv): read addr = lane*16, linear
    __shared__ __align__(16) bf16_t P_lds[4][512];
    bf16_t* Pw = &P_lds[wave][0];

    bf16x8 qfrag = *(const bf16x8*)(Qb + (size_t)lr * 256 + lg * 8);

    f32x4 oacc[2] = {};
    float lsum[4] = {};
    const f32x4 zf = {0.f, 0.f, 0.f, 0.f};

    int kv_lo = c * 1024;

    // staging role: wave 0 -> K rows 0..15, wave 1 -> K rows 16..31,
    // wave 2 -> V rows 0..15, wave 3 -> V rows 16..31 (rows per tile)
    int role = wave;
    int tlr = lr, tlg = lg;
    const bf16_t* gsrc;
    size_t gstep;
    if (role < 2) {
        gsrc = Kb + (size_t)(kv_lo + role * 16 + tlr) * 256 + tlg * 8;
        gstep = 32 * 256;
    } else {
        gsrc = Vb + (size_t)((role - 2) * 16 + tlr) * 4096 + kv_lo + tlg * 8;
        gstep = 32;
    }
    bf16_t* stage_dst = &KV[(size_t)threadIdx.x * 8];

    bf16x8 g = *(const bf16x8*)gsrc;
    gsrc += gstep;

    for (int t = 0; t < 32; t++) {
        *(bf16x8*)stage_dst = g;                       // ds_write_b128 (linear)
        if (t + 1 < 32) {                              // issue next load early
            g = *(const bf16x8*)gsrc;
            gsrc += gstep;
        }
        __syncthreads();                               // staged tile visible

        bf16x8 kf0 = *(const bf16x8*)(KV + (size_t)lane * 8);
        bf16x8 kf1 = *(const bf16x8*)(KV + 512 + (size_t)lane * 8);
        bf16x8 vf0 = *(const bf16x8*)(KV + 1024 + (size_t)lane * 8);
        bf16x8 vf1 = *(const bf16x8*)(KV + 1536 + (size_t)lane * 8);

        f32x4 s0 = __builtin_amdgcn_mfma_f32_16x16x32_bf16(qfrag, kf0, zf, 0, 0, 0);
        f32x4 s1 = __builtin_amdgcn_mfma_f32_16x16x32_bf16(qfrag, kf1, zf, 0, 0, 0);
#pragma unroll
        for (int r = 0; r < 4; r++) {
            float p0 = __expf(s0[r]);
            float p1 = __expf(s1[r]);
            lsum[r] += p0 + p1;
            // fragment-major: addr(q,kv) = (kv>>3)*128 + q*8 + (kv&7)
            Pw[((lr >> 3) * 128) + (lg * 4 + r) * 8 + (lr & 7)] = (bf16_t)p0;       // kv=lr
            Pw[((2 + (lr >> 3)) * 128) + (lg * 4 + r) * 8 + (lr & 7)] = (bf16_t)p1; // kv=16+lr
        }
        bf16x8 pf = *(const bf16x8*)(Pw + (size_t)lane * 8);
        oacc[0] = __builtin_amdgcn_mfma_f32_16x16x32_bf16(pf, vf0, oacc[0], 0, 0, 0);
        oacc[1] = __builtin_amdgcn_mfma_f32_16x16x32_bf16(pf, vf1, oacc[1], 0, 0, 0);

        __syncthreads();                               // all reads done before re-stage
    }

    // row sums: reduce across the 16 lanes (lr) sharing each lg group
#pragma unroll
    for (int r = 0; r < 4; r++) {
        float s = lsum[r];
        s += __shfl_xor(s, 1);
        s += __shfl_xor(s, 2);
        s += __shfl_xor(s, 4);
        s += __shfl_xor(s, 8);
        lsum[r] = s;
    }

    // partial writes: unnormalized O (bf16) and row-sum l (f32, lane lr==0)
#pragma unroll
    for (int r = 0; r < 4; r++) {
        int qq = q0 + lg * 4 + r;
        if (lr == 0)
            Lpart[(((size_t)c * 2 + b) * 8 + h) * 2048 + qq] = lsum[r];
#pragma unroll
        for (int ds = 0; ds < 2; ds++) {
            int dd = h * 32 + ds * 16 + lr;
            Opart[(((size_t)c * 2 + b) * 2048 + qq) * 256 + dd] = (bf16_t)oacc[ds][r];
        }
    }
}

// ---------------------------------------------------------------------------
// Kernel 4b: combine kv-split partials: o = (sum_c O_c) / (sum_c l_c).
// 131072 threads, each handles 8 contiguous cols of one row.
// ---------------------------------------------------------------------------
__global__ __launch_bounds__(256) void attn_combine(const bf16_t* __restrict__ Opart,
                                                    const float* __restrict__ Lpart,
                                                    bf16_t* __restrict__ o_buf) {
    int t = blockIdx.x * 256 + threadIdx.x;  // 0..131071
    int row = t >> 5;            // 0..4095  (b*2048+q)
    int c8 = (t & 31) * 8;       // col start, all 8 cols share one head
    int b = row >> 11, q = row & 2047, h = c8 >> 5;

    float acc[8] = {};
    float l = 0.f;
#pragma unroll
    for (int c = 0; c < 4; c++) {
        bf16x8 v = *(const bf16x8*)(Opart + (((size_t)c * 2 + b) * 2048 + q) * 256 + c8);
#pragma unroll
        for (int j = 0; j < 8; j++) acc[j] += (float)v[j];
        l += Lpart[(((size_t)c * 2 + b) * 8 + h) * 2048 + q];
    }
    float rl = 1.0f / l;
    bf16x8 o;
#pragma unroll
    for (int j = 0; j < 8; j++) o[j] = (bf16_t)(acc[j] * rl);
    *(bf16x8*)(o_buf + (size_t)row * 256 + c8) = o;
}

// ---------------------------------------------------------------------------
// Kernel 5: out = o @ out_w^T + out_b + points @ spatial_w^T + spatial_b
// ---------------------------------------------------------------------------
__global__ __launch_bounds__(256) void outproj_kernel(const bf16_t* __restrict__ o_buf,
                                                      const bf16_t* __restrict__ w_out,
                                                      const float* __restrict__ b_out,
                                                      const float* __restrict__ cur_pts,
                                                      const float* __restrict__ sw,
                                                      const float* __restrict__ sb,
                                                      float* __restrict__ out) {
    int wave = threadIdx.x >> 6, lane = threadIdx.x & 63;
    int wr = wave >> 1, wc = wave & 1;
    int m0 = blockIdx.y * 64 + wr * 32;
    int n0 = blockIdx.x * 64 + wc * 32;
    int lr = lane & 15, lg = lane >> 4;

    f32x4 acc[2][2] = {};
    for (int kc = 0; kc < 256; kc += 32) {
        bf16x8 a[2], b[2];
#pragma unroll
        for (int i = 0; i < 2; i++)
            a[i] = *(const bf16x8*)(o_buf + (size_t)(m0 + i * 16 + lr) * 256 + kc + lg * 8);
#pragma unroll
        for (int i = 0; i < 2; i++)
            b[i] = *(const bf16x8*)(w_out + (size_t)(n0 + i * 16 + lr) * 256 + kc + lg * 8);
#pragma unroll
        for (int i = 0; i < 2; i++)
#pragma unroll
            for (int j = 0; j < 2; j++)
                acc[i][j] = __builtin_amdgcn_mfma_f32_16x16x32_bf16(a[i], b[j], acc[i][j], 0, 0, 0);
    }

#pragma unroll
    for (int i = 0; i < 2; i++)
#pragma unroll
        for (int j = 0; j < 2; j++)
#pragma unroll
            for (int r = 0; r < 4; r++) {
                int mm = m0 + i * 16 + lg * 4 + r;
                int nn = n0 + j * 16 + lr;
                const float* pp = cur_pts + (size_t)mm * 3;
                float sp = pp[0] * sw[nn * 3 + 0] + pp[1] * sw[nn * 3 + 1] + pp[2] * sw[nn * 3 + 2] + sb[nn];
                out[(size_t)mm * 256 + nn] = acc[i][j][r] + b_out[nn] + sp;
            }
}

// ---------------------------------------------------------------------------
extern "C" void kernel_launch(void* const* d_in, const int* in_sizes, int n_in,
                              void* d_out, int out_size, void* d_ws, size_t ws_size,
                              hipStream_t stream) {
    const float* cur_pts  = (const float*)d_in[0];
    const float* cur_feat = (const float*)d_in[1];
    const float* nbr_pts  = (const float*)d_in[2];
    const float* nbr_feat = (const float*)d_in[3];
    const float* in_w     = (const float*)d_in[4];
    const float* in_b     = (const float*)d_in[5];
    const float* out_w    = (const float*)d_in[6];
    const float* out_b    = (const float*)d_in[7];
    const float* sw       = (const float*)d_in[8];
    const float* sb       = (const float*)d_in[9];

    char* ws = (char*)d_ws;
    bf16_t* w_in_b  = (bf16_t*)(ws + 0);          //  768*256*2 = 393216
    bf16_t* w_out_b = (bf16_t*)(ws + 393216);     //  256*256*2 = 131072
    int*    idx_buf = (int*)(ws + 524288);        //  6*2048*8*4 = 393216
    bf16_t* cur_edge = (bf16_t*)(ws + 917504);    //  4096*256*2 = 2097152
    bf16_t* all_nbr  = (bf16_t*)(ws + 3014656);   //  8192*256*2 = 4194304
    bf16_t* qp  = (bf16_t*)(ws + 7208960);        //  4096*256*2
    bf16_t* kp  = (bf16_t*)(ws + 9306112);        //  8192*256*2
    bf16_t* vpT = (bf16_t*)(ws + 13500416);       //  2*8*32*4096*2
    bf16_t* o_buf = (bf16_t*)(ws + 17694720);     //  4096*256*2 = 2097152
    bf16_t* Opart = (bf16_t*)(ws + 19791872);     //  4*2*2048*256*2 = 8388608
    float*  Lpart = (float*)(ws + 28180480);      //  4*2*8*2048*4 = 524288  (end 28704768)
    float* outp = (float*)d_out;

    wconv_kernel<<<dim3(768), dim3(256), 0, stream>>>(in_w, out_w, w_in_b, w_out_b);
    knn_kernel<<<dim3(128, 6), dim3(1024), 0, stream>>>(cur_pts, nbr_pts, idx_buf);
    edge_kernel<<<dim3(12288), dim3(64), 0, stream>>>(cur_feat, nbr_feat, idx_buf, cur_edge, all_nbr);
    qkv_kernel<<<dim3(4, 128, 3), dim3(256), 0, stream>>>(cur_edge, all_nbr, w_in_b, in_b, qp, kp, vpT);
    attn_kernel<<<dim3(32, 16, 4), dim3(256), 0, stream>>>(qp, kp, vpT, Opart, Lpart);
    attn_combine<<<dim3(512), dim3(256), 0, stream>>>(Opart, Lpart, o_buf);
    outproj_kernel<<<dim3(4, 64), dim3(256), 0, stream>>>(o_buf, w_out_b, out_b, cur_pts, sw, sb, outp);
}

// Round 8
// 202.456 us; speedup vs baseline: 1.0965x; 1.0009x over previous
//
#include <hip/hip_runtime.h>
#include <hip/hip_bf16.h>

typedef __bf16 bf16_t;
typedef __attribute__((ext_vector_type(8))) __bf16 bf16x8;
typedef __attribute__((ext_vector_type(4))) __bf16 bf16x4;
typedef __attribute__((ext_vector_type(4))) float f32x4;

// Problem constants
// B=2, N=2048, D=256, H=8, M=2, NN=2048, K=8, dh=32

// ---------------------------------------------------------------------------
// Kernel 0: convert weights to bf16
// ---------------------------------------------------------------------------
__global__ __launch_bounds__(256) void wconv_kernel(const float* __restrict__ w_in,
                                                    const float* __restrict__ w_out,
                                                    bf16_t* __restrict__ w_in_b,
                                                    bf16_t* __restrict__ w_out_b) {
    int i = blockIdx.x * 256 + threadIdx.x;
    if (i < 768 * 256) w_in_b[i] = (bf16_t)w_in[i];
    if (i < 256 * 256) w_out_b[i] = (bf16_t)w_out[i];
}

// ---------------------------------------------------------------------------
// Kernel 1: KNN top-8, one WAVE per query. 16 queries per 1024-thread block;
// block stages all 2048 points (x,y,z,|p|^2) in LDS once. Each lane keeps a
// sorted top-8 of its 32 candidates (j = t*64 + lane, stride-1 LDS reads,
// within-lane idx ascending), then 8 rounds of wave-wide lexicographic
// (d2, idx) min via shfl_xor + pop-shift. Matches lax.top_k stable ordering.
// Distance formula replicates reference fp32 evaluation order, no fma.
// ---------------------------------------------------------------------------
__global__ __launch_bounds__(1024) void knn_kernel(const float* __restrict__ cur_pts,
                                                   const float* __restrict__ nbr_pts,
                                                   int* __restrict__ idx_out) {
    int p = blockIdx.y;  // 0..5 : 0,1 = current batches; 2..5 = (m*2+b)
    const float* pts = (p < 2) ? (cur_pts + (size_t)p * 2048 * 3)
                               : (nbr_pts + (size_t)(p - 2) * 2048 * 3);

    __shared__ __align__(16) float4 spts[2048];

    int tid = threadIdx.x;
    for (int i = tid; i < 2048; i += 1024) {
        float x = pts[i * 3 + 0], y = pts[i * 3 + 1], z = pts[i * 3 + 2];
        float sq = __fadd_rn(__fadd_rn(__fmul_rn(x, x), __fmul_rn(y, y)), __fmul_rn(z, z));
        spts[i] = make_float4(x, y, z, sq);
    }
    __syncthreads();

    int wave = tid >> 6, lane = tid & 63;
    int q = blockIdx.x * 16 + wave;
    float4 qp4 = spts[q];

    float dist[8];
    int di[8];
#pragma unroll
    for (int r = 0; r < 8; r++) { dist[r] = 3.4e38f; di[r] = 0x7fffffff; }

    for (int t = 0; t < 32; t++) {
        int j = t * 64 + lane;
        float4 pp = spts[j];
        float dot = __fadd_rn(__fadd_rn(__fmul_rn(qp4.x, pp.x), __fmul_rn(qp4.y, pp.y)),
                              __fmul_rn(qp4.z, pp.z));
        float d2 = __fsub_rn(__fadd_rn(qp4.w, pp.w), __fmul_rn(2.0f, dot));
        if (d2 < dist[7]) {
#pragma unroll
            for (int r = 7; r >= 1; --r) {
                bool cm = d2 < dist[r - 1];
                bool cr = d2 < dist[r];
                float nd = cm ? dist[r - 1] : (cr ? d2 : dist[r]);
                int ni = cm ? di[r - 1] : (cr ? j : di[r]);
                dist[r] = nd; di[r] = ni;
            }
            if (d2 < dist[0]) { dist[0] = d2; di[0] = j; }
        }
    }

    // 8 rounds: wave-wide lexicographic (d2, idx) min, winner lane pops.
    int res[8];
#pragma unroll
    for (int r = 0; r < 8; r++) {
        float bd = dist[0];
        int bi = di[0];
#pragma unroll
        for (int m = 1; m < 64; m <<= 1) {
            float od = __shfl_xor(bd, m);
            int oi = __shfl_xor(bi, m);
            if (od < bd || (od == bd && oi < bi)) { bd = od; bi = oi; }
        }
        res[r] = bi;
        bool win = (di[0] == bi);
#pragma unroll
        for (int k = 0; k < 7; k++) {
            dist[k] = win ? dist[k + 1] : dist[k];
            di[k]   = win ? di[k + 1]   : di[k];
        }
        if (win) { dist[7] = 3.4e38f; di[7] = 0x7fffffff; }
    }

    if (lane == 0) {
        int4* o = (int4*)(idx_out + ((size_t)p * 2048 + q) * 8);
        o[0] = make_int4(res[0], res[1], res[2], res[3]);
        o[1] = make_int4(res[4], res[5], res[6], res[7]);
    }
}

// ---------------------------------------------------------------------------
// Kernel 2: gather neighbor features, edge = f - mean(nbr). One block per
// query (64 threads x float4). Writes bf16 edge features in the layouts the
// GEMMs consume (cur_edge [B*N,256]; all_nbr [B, M*NN, 256]).
// ---------------------------------------------------------------------------
__global__ __launch_bounds__(64) void edge_kernel(const float* __restrict__ cur_feat,
                                                  const float* __restrict__ nbr_feat,
                                                  const int* __restrict__ idx_buf,
                                                  bf16_t* __restrict__ cur_edge,
                                                  bf16_t* __restrict__ all_nbr) {
    int blk = blockIdx.x;
    int p = blk >> 11, q = blk & 2047;
    const float* feat;
    bf16_t* outp;
    if (p < 2) {
        feat = cur_feat + (size_t)p * 2048 * 256;
        outp = cur_edge + ((size_t)p * 2048 + q) * 256;
    } else {
        int mb = p - 2;
        int m = mb >> 1, bb = mb & 1;
        feat = nbr_feat + (size_t)mb * 2048 * 256;
        outp = all_nbr + ((size_t)bb * 4096 + m * 2048 + q) * 256;
    }
    const int* idx = idx_buf + ((size_t)p * 2048 + q) * 8;
    int t = threadIdx.x;
    float4 self = ((const float4*)(feat + (size_t)q * 256))[t];
    float sx = 0.f, sy = 0.f, sz = 0.f, sw = 0.f;
#pragma unroll
    for (int r = 0; r < 8; r++) {
        float4 f = ((const float4*)(feat + (size_t)idx[r] * 256))[t];
        sx += f.x; sy += f.y; sz += f.z; sw += f.w;
    }
    bf16x4 v;
    v[0] = (bf16_t)(self.x - sx * 0.125f);
    v[1] = (bf16_t)(self.y - sy * 0.125f);
    v[2] = (bf16_t)(self.z - sz * 0.125f);
    v[3] = (bf16_t)(self.w - sw * 0.125f);
    *(bf16x4*)(outp + 4 * t) = v;
}

// ---------------------------------------------------------------------------
// Kernel 3: QKV projections via bf16 MFMA. z=0: qp (scaled by 1/sqrt(32)),
// z=1: kp, z=2: vp stored transposed per head [b,h,dh,kv].
// Block 256 = 4 waves of 32x32 -> 64x64 tile, K=256.
// ---------------------------------------------------------------------------
__global__ __launch_bounds__(256) void qkv_kernel(const bf16_t* __restrict__ cur_edge,
                                                  const bf16_t* __restrict__ all_nbr,
                                                  const bf16_t* __restrict__ w_in,
                                                  const float* __restrict__ b_in,
                                                  bf16_t* __restrict__ qp,
                                                  bf16_t* __restrict__ kp,
                                                  bf16_t* __restrict__ vpT) {
    int z = blockIdx.z;
    int Mrows = (z == 0) ? 4096 : 8192;
    int m0base = blockIdx.y * 64;
    if (m0base >= Mrows) return;
    const bf16_t* A = (z == 0) ? cur_edge : all_nbr;
    const bf16_t* W = w_in + (size_t)z * 256 * 256;

    int wave = threadIdx.x >> 6, lane = threadIdx.x & 63;
    int wr = wave >> 1, wc = wave & 1;
    int m0 = m0base + wr * 32;
    int n0 = blockIdx.x * 64 + wc * 32;
    int lr = lane & 15, lg = lane >> 4;

    f32x4 acc[2][2] = {};
    for (int kc = 0; kc < 256; kc += 32) {
        bf16x8 a[2], b[2];
#pragma unroll
        for (int i = 0; i < 2; i++)
            a[i] = *(const bf16x8*)(A + (size_t)(m0 + i * 16 + lr) * 256 + kc + lg * 8);
#pragma unroll
        for (int i = 0; i < 2; i++)
            b[i] = *(const bf16x8*)(W + (size_t)(n0 + i * 16 + lr) * 256 + kc + lg * 8);
#pragma unroll
        for (int i = 0; i < 2; i++)
#pragma unroll
            for (int j = 0; j < 2; j++)
                acc[i][j] = __builtin_amdgcn_mfma_f32_16x16x32_bf16(a[i], b[j], acc[i][j], 0, 0, 0);
    }

    const float inv_s = 0.17677669529663687f;  // 1/sqrt(32)
#pragma unroll
    for (int i = 0; i < 2; i++)
#pragma unroll
        for (int j = 0; j < 2; j++)
#pragma unroll
            for (int r = 0; r < 4; r++) {
                int mm = m0 + i * 16 + lg * 4 + r;
                int nn = n0 + j * 16 + lr;
                float v = acc[i][j][r] + b_in[z * 256 + nn];
                if (z == 0) {
                    qp[(size_t)mm * 256 + nn] = (bf16_t)(v * inv_s);
                } else if (z == 1) {
                    kp[(size_t)mm * 256 + nn] = (bf16_t)v;
                } else {
                    int bb = mm >> 12, kv = mm & 4095, h = nn >> 5, dd = nn & 31;
                    vpT[(((size_t)bb * 8 + h) * 32 + dd) * 4096 + kv] = (bf16_t)v;
                }
            }
}

// ---------------------------------------------------------------------------
// Kernel 4: cross attention, kv-SPLIT partial softmax, 2-phase pipelined
// cooperative staging (T3/T4 pattern in plain HIP):
//   - double-buffered 4KB KV tile in LDS; ONE raw s_barrier per tile
//     (s_waitcnt lgkmcnt(0) + sched_barrier fences; NO vmcnt drain, so
//     prefetch loads stay in flight across the barrier).
//   - depth-2/3 register prefetch with STATIC rotation (gA/gB, unroll-2):
//     tile t's global load issues ~2 barriers before its ds_write; the
//     compiler's counted vmcnt at the ds_write is the T4 wait.
//   - bijective XCD swizzle: 1-D grid 2048 = (xcd, 32 q-blocks, 8 groups);
//     all 32 q-blocks sharing one (bh,c) K/V slice land on one XCD's L2.
//   - no max-subtraction (|s|<<1): partials combine by addition downstream.
// ---------------------------------------------------------------------------
__global__ __launch_bounds__(256, 8) void attn_kernel(const bf16_t* __restrict__ qp,
                                                      const bf16_t* __restrict__ kp,
                                                      const bf16_t* __restrict__ vpT,
                                                      bf16_t* __restrict__ Opart,
                                                      float* __restrict__ Lpart) {
    // XCD-aware decode: d%8 = XCD (round-robin dispatch heuristic)
    int d = blockIdx.x;
    int xcd = d & 7;
    int j = d >> 3;               // 0..255
    int xb = j & 31;              // q-tile 0..31
    int g = xcd + 8 * (j >> 5);   // group 0..63, constant per XCD-slice
    int bh = g & 15, c = g >> 4;
    int b = bh >> 3, h = bh & 7;

    int wave = threadIdx.x >> 6, lane = threadIdx.x & 63;
    int lr = lane & 15, lg = lane >> 4;
    int q0 = xb * 64 + wave * 16;

    const bf16_t* Qb = qp + ((size_t)b * 2048 + q0) * 256 + h * 32;
    const bf16_t* Kb = kp + (size_t)b * 4096 * 256 + h * 32;
    const bf16_t* Vb = vpT + ((size_t)b * 8 + h) * 32 * 4096;

    // double-buffered fragment-major K/V tile (per buffer: 2048 bf16 = 4KB)
    __shared__ __align__(16) bf16_t KV[2][2048];
    // per-wave fragment-major P (16 q x 32 kv): read addr = lane*16, linear
    __shared__ __align__(16) bf16_t P_lds[4][512];
    bf16_t* Pw = &P_lds[wave][0];

    bf16x8 qfrag = *(const bf16x8*)(Qb + (size_t)lr * 256 + lg * 8);

    f32x4 oacc[2] = {};
    float lsum[4] = {};
    const f32x4 zf = {0.f, 0.f, 0.f, 0.f};

    int kv_lo = c * 1024;

    // staging role: wave 0 -> K rows 0..15, wave 1 -> K rows 16..31,
    // wave 2 -> V rows 0..15, wave 3 -> V rows 16..31 (per 32-kv tile)
    const bf16_t* gsrc;
    size_t gstep;
    if (wave < 2) {
        gsrc = Kb + (size_t)(kv_lo + wave * 16 + lr) * 256 + lg * 8;
        gstep = 32 * 256;
    } else {
        gsrc = Vb + (size_t)((wave - 2) * 16 + lr) * 4096 + kv_lo + lg * 8;
        gstep = 32;
    }
    const int sdst = threadIdx.x * 8;  // linear ds_write_b128 dest (elems)

#define BARRIER()                                          \
    asm volatile("s_waitcnt lgkmcnt(0)" ::: "memory");     \
    __builtin_amdgcn_sched_barrier(0);                     \
    __builtin_amdgcn_s_barrier();                          \
    __builtin_amdgcn_sched_barrier(0);

#define COMPUTE(BUF)                                                           \
    {                                                                          \
        bf16x8 kf0 = *(const bf16x8*)(&KV[BUF][0] + (size_t)lane * 8);         \
        bf16x8 kf1 = *(const bf16x8*)(&KV[BUF][512] + (size_t)lane * 8);       \
        bf16x8 vf0 = *(const bf16x8*)(&KV[BUF][1024] + (size_t)lane * 8);      \
        bf16x8 vf1 = *(const bf16x8*)(&KV[BUF][1536] + (size_t)lane * 8);      \
        f32x4 s0 = __builtin_amdgcn_mfma_f32_16x16x32_bf16(qfrag, kf0, zf, 0, 0, 0); \
        f32x4 s1 = __builtin_amdgcn_mfma_f32_16x16x32_bf16(qfrag, kf1, zf, 0, 0, 0); \
        _Pragma("unroll")                                                      \
        for (int r = 0; r < 4; r++) {                                          \
            float p0 = __expf(s0[r]);                                          \
            float p1 = __expf(s1[r]);                                          \
            lsum[r] += p0 + p1;                                                \
            Pw[((lr >> 3) * 128) + (lg * 4 + r) * 8 + (lr & 7)] = (bf16_t)p0;  \
            Pw[((2 + (lr >> 3)) * 128) + (lg * 4 + r) * 8 + (lr & 7)] = (bf16_t)p1; \
        }                                                                      \
        bf16x8 pf = *(const bf16x8*)(Pw + (size_t)lane * 8);                   \
        oacc[0] = __builtin_amdgcn_mfma_f32_16x16x32_bf16(pf, vf0, oacc[0], 0, 0, 0); \
        oacc[1] = __builtin_amdgcn_mfma_f32_16x16x32_bf16(pf, vf1, oacc[1], 0, 0, 0); \
    }

    // prologue: tiles 0,1,2 in flight; stage tile 0 into buf0
    bf16x8 g0 = *(const bf16x8*)gsrc; gsrc += gstep;
    bf16x8 gA = *(const bf16x8*)gsrc; gsrc += gstep;  // tile 1
    bf16x8 gB = *(const bf16x8*)gsrc; gsrc += gstep;  // tile 2
    *(bf16x8*)(&KV[0][0] + sdst) = g0;                // waits tile0 only
    BARRIER()

#pragma unroll 1
    for (int i = 0; i < 16; i++) {
        // ---- step A: compute tile 2i (buf0); write tile 2i+1 -> buf1
        bf16x8 gA2, gB2;
        if (i < 15) { gA2 = *(const bf16x8*)gsrc; gsrc += gstep; }  // tile 2i+3
        __builtin_amdgcn_sched_barrier(0);
        COMPUTE(0)
        *(bf16x8*)(&KV[1][0] + sdst) = gA;            // compiler: vmcnt(counted)
        BARRIER()
        // ---- step B: compute tile 2i+1 (buf1); write tile 2i+2 -> buf0
        if (i < 14) { gB2 = *(const bf16x8*)gsrc; gsrc += gstep; }  // tile 2i+4
        __builtin_amdgcn_sched_barrier(0);
        COMPUTE(1)
        if (i < 15) {
            *(bf16x8*)(&KV[0][0] + sdst) = gB;
            BARRIER()
        }
        gA = gA2; gB = gB2;
    }
#undef COMPUTE
#undef BARRIER

    // row sums: reduce across the 16 lanes (lr) sharing each lg group
#pragma unroll
    for (int r = 0; r < 4; r++) {
        float s = lsum[r];
        s += __shfl_xor(s, 1);
        s += __shfl_xor(s, 2);
        s += __shfl_xor(s, 4);
        s += __shfl_xor(s, 8);
        lsum[r] = s;
    }

    // partial writes: unnormalized O (bf16) and row-sum l (f32, lane lr==0)
#pragma unroll
    for (int r = 0; r < 4; r++) {
        int qq = q0 + lg * 4 + r;
        if (lr == 0)
            Lpart[(((size_t)c * 2 + b) * 8 + h) * 2048 + qq] = lsum[r];
#pragma unroll
        for (int ds = 0; ds < 2; ds++) {
            int dd = h * 32 + ds * 16 + lr;
            Opart[(((size_t)c * 2 + b) * 2048 + qq) * 256 + dd] = (bf16_t)oacc[ds][r];
        }
    }
}

// ---------------------------------------------------------------------------
// Kernel 4b: combine kv-split partials: o = (sum_c O_c) / (sum_c l_c).
// 131072 threads, each handles 8 contiguous cols of one row.
// ---------------------------------------------------------------------------
__global__ __launch_bounds__(256) void attn_combine(const bf16_t* __restrict__ Opart,
                                                    const float* __restrict__ Lpart,
                                                    bf16_t* __restrict__ o_buf) {
    int t = blockIdx.x * 256 + threadIdx.x;  // 0..131071
    int row = t >> 5;            // 0..4095  (b*2048+q)
    int c8 = (t & 31) * 8;       // col start, all 8 cols share one head
    int b = row >> 11, q = row & 2047, h = c8 >> 5;

    float acc[8] = {};
    float l = 0.f;
#pragma unroll
    for (int c = 0; c < 4; c++) {
        bf16x8 v = *(const bf16x8*)(Opart + (((size_t)c * 2 + b) * 2048 + q) * 256 + c8);
#pragma unroll
        for (int j = 0; j < 8; j++) acc[j] += (float)v[j];
        l += Lpart[(((size_t)c * 2 + b) * 8 + h) * 2048 + q];
    }
    float rl = 1.0f / l;
    bf16x8 o;
#pragma unroll
    for (int j = 0; j < 8; j++) o[j] = (bf16_t)(acc[j] * rl);
    *(bf16x8*)(o_buf + (size_t)row * 256 + c8) = o;
}

// ---------------------------------------------------------------------------
// Kernel 5: out = o @ out_w^T + out_b + points @ spatial_w^T + spatial_b
// ---------------------------------------------------------------------------
__global__ __launch_bounds__(256) void outproj_kernel(const bf16_t* __restrict__ o_buf,
                                                      const bf16_t* __restrict__ w_out,
                                                      const float* __restrict__ b_out,
                                                      const float* __restrict__ cur_pts,
                                                      const float* __restrict__ sw,
                                                      const float* __restrict__ sb,
                                                      float* __restrict__ out) {
    int wave = threadIdx.x >> 6, lane = threadIdx.x & 63;
    int wr = wave >> 1, wc = wave & 1;
    int m0 = blockIdx.y * 64 + wr * 32;
    int n0 = blockIdx.x * 64 + wc * 32;
    int lr = lane & 15, lg = lane >> 4;

    f32x4 acc[2][2] = {};
    for (int kc = 0; kc < 256; kc += 32) {
        bf16x8 a[2], b[2];
#pragma unroll
        for (int i = 0; i < 2; i++)
            a[i] = *(const bf16x8*)(o_buf + (size_t)(m0 + i * 16 + lr) * 256 + kc + lg * 8);
#pragma unroll
        for (int i = 0; i < 2; i++)
            b[i] = *(const bf16x8*)(w_out + (size_t)(n0 + i * 16 + lr) * 256 + kc + lg * 8);
#pragma unroll
        for (int i = 0; i < 2; i++)
#pragma unroll
            for (int j = 0; j < 2; j++)
                acc[i][j] = __builtin_amdgcn_mfma_f32_16x16x32_bf16(a[i], b[j], acc[i][j], 0, 0, 0);
    }

#pragma unroll
    for (int i = 0; i < 2; i++)
#pragma unroll
        for (int j = 0; j < 2; j++)
#pragma unroll
            for (int r = 0; r < 4; r++) {
                int mm = m0 + i * 16 + lg * 4 + r;
                int nn = n0 + j * 16 + lr;
                const float* pp = cur_pts + (size_t)mm * 3;
                float sp = pp[0] * sw[nn * 3 + 0] + pp[1] * sw[nn * 3 + 1] + pp[2] * sw[nn * 3 + 2] + sb[nn];
                out[(size_t)mm * 256 + nn] = acc[i][j][r] + b_out[nn] + sp;
            }
}

// ---------------------------------------------------------------------------
extern "C" void kernel_launch(void* const* d_in, const int* in_sizes, int n_in,
                              void* d_out, int out_size, void* d_ws, size_t ws_size,
                              hipStream_t stream) {
    const float* cur_pts  = (const float*)d_in[0];
    const float* cur_feat = (const float*)d_in[1];
    const float* nbr_pts  = (const float*)d_in[2];
    const float* nbr_feat = (const float*)d_in[3];
    const float* in_w     = (const float*)d_in[4];
    const float* in_b     = (const float*)d_in[5];
    const float* out_w    = (const float*)d_in[6];
    const float* out_b    = (const float*)d_in[7];
    const float* sw       = (const float*)d_in[8];
    const float* sb       = (const float*)d_in[9];

    char* ws = (char*)d_ws;
    bf16_t* w_in_b  = (bf16_t*)(ws + 0);          //  768*256*2 = 393216
    bf16_t* w_out_b = (bf16_t*)(ws + 393216);     //  256*256*2 = 131072
    int*    idx_buf = (int*)(ws + 524288);        //  6*2048*8*4 = 393216
    bf16_t* cur_edge = (bf16_t*)(ws + 917504);    //  4096*256*2 = 2097152
    bf16_t* all_nbr  = (bf16_t*)(ws + 3014656);   //  8192*256*2 = 4194304
    bf16_t* qp  = (bf16_t*)(ws + 7208960);        //  4096*256*2
    bf16_t* kp  = (bf16_t*)(ws + 9306112);        //  8192*256*2
    bf16_t* vpT = (bf16_t*)(ws + 13500416);       //  2*8*32*4096*2
    bf16_t* o_buf = (bf16_t*)(ws + 17694720);     //  4096*256*2 = 2097152
    bf16_t* Opart = (bf16_t*)(ws + 19791872);     //  4*2*2048*256*2 = 8388608
    float*  Lpart = (float*)(ws + 28180480);      //  4*2*8*2048*4 = 524288  (end 28704768)
    float* outp = (float*)d_out;

    wconv_kernel<<<dim3(768), dim3(256), 0, stream>>>(in_w, out_w, w_in_b, w_out_b);
    knn_kernel<<<dim3(128, 6), dim3(1024), 0, stream>>>(cur_pts, nbr_pts, idx_buf);
    edge_kernel<<<dim3(12288), dim3(64), 0, stream>>>(cur_feat, nbr_feat, idx_buf, cur_edge, all_nbr);
    qkv_kernel<<<dim3(4, 128, 3), dim3(256), 0, stream>>>(cur_edge, all_nbr, w_in_b, in_b, qp, kp, vpT);
    attn_kernel<<<dim3(2048), dim3(256), 0, stream>>>(qp, kp, vpT, Opart, Lpart);
    attn_combine<<<dim3(512), dim3(256), 0, stream>>>(Opart, Lpart, o_buf);
    outproj_kernel<<<dim3(4, 64), dim3(256), 0, stream>>>(o_buf, w_out_b, out_b, cur_pts, sw, sb, outp);
}